// Round 10
// baseline (544.881 us; speedup 1.0000x reference)
//
#include <hip/hip_runtime.h>
#include <hip/hip_bf16.h>
#include <math.h>

typedef __bf16 bf16;
typedef __bf16 bf16x8 __attribute__((ext_vector_type(8)));
typedef short bf16x4s __attribute__((ext_vector_type(4)));
typedef float f32x4 __attribute__((ext_vector_type(4)));

#define DIM 768
#define NH 12
#define HD 64
#define HID 3072
#define BB 4
#define SS 2048
#define QPRESCALE 0.18033688011112042f /* (1/8) * log2(e) */

#define MFMA(a, b, c) __builtin_amdgcn_mfma_f32_16x16x32_bf16(a, b, c, 0, 0, 0)
#define MFMA16(a, b, c) \
  __builtin_amdgcn_mfma_f32_16x16x16bf16_1k(a, b, c, 0, 0, 0)

__device__ __forceinline__ void gld16(const void* g, void* l) {
  __builtin_amdgcn_global_load_lds(
      (const __attribute__((address_space(1))) void*)g,
      (__attribute__((address_space(3))) void*)l, 16, 0, 0);
}

__device__ __forceinline__ unsigned pk2(float a, float b) {
  union {
    bf16 h[2];
    unsigned u;
  } t;
  t.h[0] = (bf16)a;
  t.h[1] = (bf16)b;
  return t.u;
}

// ---------------- fused weight cast + transpose: fp32 [R][C] -> bf16 [C][R] -
__global__ __launch_bounds__(256) void castT_all_kernel(
    const float* __restrict__ s0, bf16* __restrict__ d0,
    const float* __restrict__ s1, bf16* __restrict__ d1,
    const float* __restrict__ s2, bf16* __restrict__ d2,
    const float* __restrict__ s3, bf16* __restrict__ d3) {
  __shared__ float tile[32][33];
  int id = blockIdx.x;
  const float* in;
  bf16* out;
  int R, C, loc;
  if (id < 1728) { in = s0; out = d0; R = 768; C = 2304; loc = id; }
  else if (id < 2304) { in = s1; out = d1; R = 768; C = 768; loc = id - 1728; }
  else if (id < 4608) { in = s2; out = d2; R = 768; C = 3072; loc = id - 2304; }
  else { in = s3; out = d3; R = 3072; C = 768; loc = id - 4608; }
  const int cb = C >> 5;
  const int c0 = (loc % cb) * 32, r0 = (loc / cb) * 32;
  const int tx = threadIdx.x & 31, ty = threadIdx.x >> 5;  // ty 0..7
#pragma unroll
  for (int i = 0; i < 32; i += 8)
    tile[ty + i][tx] = in[(size_t)(r0 + ty + i) * C + c0 + tx];
  __syncthreads();
#pragma unroll
  for (int i = 0; i < 32; i += 8)
    out[(size_t)(c0 + ty + i) * R + r0 + tx] = (bf16)tile[tx][ty + i];
}

// ---------------- mask int32 [B][1][S][S] -> bitmask [B][S][S/32] ----------
__global__ __launch_bounds__(256) void maskbits_kernel(
    const int* __restrict__ mask, unsigned* __restrict__ bits) {
  const int i = blockIdx.x * 256 + threadIdx.x;
  unsigned long long m = __ballot(mask[i] != 0);
  const int lane = threadIdx.x & 63;
  if (lane == 0) bits[i >> 5] = (unsigned)m;
  else if (lane == 32) bits[i >> 5] = (unsigned)(m >> 32);
}

// ---------------- LayerNorm fp32 row(768) -> bf16 --------------------------
__global__ __launch_bounds__(256) void ln_kernel(
    const float* __restrict__ x, const float* __restrict__ g,
    const float* __restrict__ beta, bf16* __restrict__ out) {
  const int row = blockIdx.x, t = threadIdx.x;
  const float* xr = x + (size_t)row * DIM;
  float v0 = xr[t], v1 = xr[t + 256], v2 = xr[t + 512];
  float s = v0 + v1 + v2;
  float s2 = v0 * v0 + v1 * v1 + v2 * v2;
#pragma unroll
  for (int d = 1; d < 64; d <<= 1) {
    s += __shfl_xor(s, d);
    s2 += __shfl_xor(s2, d);
  }
  __shared__ float red[8];
  const int wv = t >> 6, lane = t & 63;
  if (lane == 0) { red[wv] = s; red[wv + 4] = s2; }
  __syncthreads();
  s = red[0] + red[1] + red[2] + red[3];
  s2 = red[4] + red[5] + red[6] + red[7];
  const float mu = s * (1.0f / DIM);
  const float var = s2 * (1.0f / DIM) - mu * mu;
  const float r = rsqrtf(var + 1e-6f);
  bf16* o = out + (size_t)row * DIM;
  o[t] = (bf16)((v0 - mu) * r * g[t] + beta[t]);
  o[t + 256] = (bf16)((v1 - mu) * r * g[t + 256] + beta[t + 256]);
  o[t + 512] = (bf16)((v2 - mu) * r * g[t + 512] + beta[t + 512]);
}

// ---------------- GEMM: A[M][K] bf16 x Bt[N][K] bf16 -> epilogue -----------
// TM=128, TN=64, BK=32: 4 waves of 32x64. Double-buffered LDS is now only
// 24 KB -> 4 blocks/CU (register-capped), vs 48 KB/3 at BK=64. One barrier
// per iter; stage(next) issued right after the barrier into buf^1.
// Staging swizzle (rows are 64B = half a bank period): lane l sources global
// chunk (l&3)^((l>>3)&3), lands at phys chunk l&3; fragment read of logical
// chunk `quad` of row r is at phys quad^((r>>1)&3) -> 2-way aliasing (free).
enum { EPI_QKV = 0, EPI_PROJ = 1, EPI_FFN1 = 2, EPI_FFN2 = 3 };

template <int EPI, int K>
__global__ __launch_bounds__(256) void gemm_kernel(
    const bf16* __restrict__ A, const bf16* __restrict__ Bt,
    const float* __restrict__ bias, const float* __restrict__ res,
    void* __restrict__ o0, void* __restrict__ o1, void* __restrict__ o2) {
  constexpr int NIT = K / 32;
  __shared__ bf16 As[2][128 * 32];
  __shared__ bf16 Bs[2][64 * 32];
  const int tid = threadIdx.x;
  const int wv = tid >> 6, lane = tid & 63;
  const int quad = lane >> 4, l15 = lane & 15;
  const int l2 = lane >> 2, c4 = lane & 3, ssw = (lane >> 3) & 3;
  const int m0 = blockIdx.y * 128, n0 = blockIdx.x * 64;
  const int wm = wv * 32;

  f32x4 acc[2][4] = {};

  const int gch = (c4 ^ ssw) * 8;
  const bf16* Ag = A + (size_t)(m0 + wv * 32 + l2) * K + gch;
  const bf16* Bg = Bt + (size_t)(n0 + wv * 16 + l2) * K + gch;

  auto stage = [&](int buf, int k0) {
    gld16(Ag + k0, &As[buf][(wv * 32) * 32]);
    gld16(Ag + (size_t)16 * K + k0, &As[buf][(wv * 32 + 16) * 32]);
    gld16(Bg + k0, &Bs[buf][(wv * 16) * 32]);
  };

  stage(0, 0);
  const int fsw = (l15 >> 1) & 3;
  const int pch = ((quad ^ fsw) & 3) * 8;

  for (int it = 0; it < NIT; ++it) {
    __syncthreads();  // drains this iter's DMAs (issued one compute ago)
    if (it + 1 < NIT) stage((it + 1) & 1, (it + 1) * 32);
    const bf16* Ab = As[it & 1];
    const bf16* Bb = Bs[it & 1];
    bf16x8 af[2], bfr[4];
#pragma unroll
    for (int i = 0; i < 2; i++) {
      const int ra = wm + i * 16 + l15;
      af[i] = *(const bf16x8*)&Ab[ra * 32 + pch];
    }
#pragma unroll
    for (int i = 0; i < 4; i++) {
      const int rb = i * 16 + l15;
      bfr[i] = *(const bf16x8*)&Bb[rb * 32 + pch];
    }
#pragma unroll
    for (int mi = 0; mi < 2; mi++)
#pragma unroll
      for (int ni = 0; ni < 4; ni++)
        acc[mi][ni] = MFMA(af[mi], bfr[ni], acc[mi][ni]);
  }

  // epilogue: C layout col=lane&15, row=quad*4+reg
#pragma unroll
  for (int mi = 0; mi < 2; mi++) {
#pragma unroll
    for (int ni = 0; ni < 4; ni++) {
      const int n = n0 + ni * 16 + l15;
      const float bv = bias[n];
      const int mb = m0 + wm + mi * 16 + quad * 4;
      float val[4];
#pragma unroll
      for (int r = 0; r < 4; r++) val[r] = acc[mi][ni][r] + bv;
      if (EPI == EPI_QKV) {
        const int which = n / 768;
        const int nn = n - which * 768;
        const int hh = nn >> 6, d = nn & 63;
        const int bb = mb >> 11, s = mb & 2047;
        if (which == 0) {
#pragma unroll
          for (int r = 0; r < 4; r++)
            ((bf16*)o0)[((size_t)(bb * NH + hh) * SS + s + r) * HD + d] =
                (bf16)(val[r] * QPRESCALE);
        } else if (which == 1) {
#pragma unroll
          for (int r = 0; r < 4; r++)
            ((bf16*)o1)[((size_t)(bb * NH + hh) * SS + s + r) * HD + d] =
                (bf16)val[r];
        } else {
          // V transposed [bh][d][s]: 4 consecutive s -> packed 8B store
          uint2 pv;
          pv.x = pk2(val[0], val[1]);
          pv.y = pk2(val[2], val[3]);
          *(uint2*)&((bf16*)o2)[((size_t)(bb * NH + hh) * HD + d) * SS + s] = pv;
        }
      } else if (EPI == EPI_PROJ) {
#pragma unroll
        for (int r = 0; r < 4; r++)
          ((float*)o0)[(size_t)(mb + r) * DIM + n] =
              res[(size_t)(mb + r) * DIM + n] + val[r];
      } else if (EPI == EPI_FFN1) {
#pragma unroll
        for (int r = 0; r < 4; r++) {
          const float ge =
              0.5f * val[r] * (1.0f + erff(val[r] * 0.70710678118654752f));
          ((bf16*)o0)[(size_t)(mb + r) * HID + n] = (bf16)ge;
        }
      } else {  // EPI_FFN2
#pragma unroll
        for (int r = 0; r < 4; r++)
          ((float*)o0)[(size_t)(mb + r) * DIM + n] =
              res[(size_t)(mb + r) * DIM + n] + val[r];
      }
    }
  }
}

// ---------------- flash attention, k-split x2 -------------------------------
// Sᵀ = MFMA(kfrag, qfrag) -> C layout (col=q, row=k) IS mfma16's B-frag
// layout, so PV needs no P movement. lsum via ones-A MFMA16. Mask via LDS
// LUT on packed P. 128 q-rows/block, 2 k-slices (blockIdx.x&1): each block
// covers 1024 keys and writes fp32 partial O + partial lsum; a reduce kernel
// combines. Grid 1536 blocks -> 4 blocks/CU (reg-capped, was grid-capped 3).
// K/V double-buffered, one barrier per tile.
__global__ __launch_bounds__(256) void attn_kernel(
    const bf16* __restrict__ q, const bf16* __restrict__ k,
    const bf16* __restrict__ vT, const unsigned* __restrict__ bits,
    float* __restrict__ Opart, float* __restrict__ Lpart) {
  const int b = blockIdx.z, h = blockIdx.y;
  const int ksl = blockIdx.x & 1, q0 = (blockIdx.x >> 1) * 128;
  const int kbase = ksl * (SS / 2);
  const int tid = threadIdx.x, wv = tid >> 6, lane = tid & 63;
  const int quad = lane >> 4, l15 = lane & 15;
  const int lrow = lane >> 3, lcol = lane & 7;

  __shared__ bf16 Ks[2][64 * 64];
  __shared__ bf16 Vs[2][64 * 64];
  __shared__ unsigned lut[32];

  if (tid < 16) {
    lut[2 * tid] =
        ((tid & 1) ? 0xFFFFu : 0u) | ((tid & 2) ? 0xFFFF0000u : 0u);
    lut[2 * tid + 1] =
        ((tid & 4) ? 0xFFFFu : 0u) | ((tid & 8) ? 0xFFFF0000u : 0u);
  }

  const bf16* qbh = q + (size_t)(b * NH + h) * SS * HD;
  const bf16* kbh = k + (size_t)(b * NH + h) * SS * HD;
  const bf16* vbh = vT + (size_t)(b * NH + h) * HD * SS;

  // Q fragments (B-operand for Sᵀ): q-row = q0 + wv*32 + mi*16 + l15
  bf16x8 aq[2][2];
#pragma unroll
  for (int mi = 0; mi < 2; mi++)
#pragma unroll
    for (int ks = 0; ks < 2; ks++) {
      const int s = q0 + wv * 32 + mi * 16 + l15;
      aq[mi][ks] = *(const bf16x8*)&qbh[(size_t)s * HD + ks * 32 + quad * 8];
    }

  const unsigned long long* mrow[2];
#pragma unroll
  for (int mi = 0; mi < 2; mi++)
    mrow[mi] = (const unsigned long long*)bits +
               (size_t)(b * SS + q0 + wv * 32 + mi * 16 + l15) * 32 +
               (kbase >> 6);

  f32x4 O[2][4] = {};
  f32x4 lm[2] = {};
  const short oneb = 0x3F80;
  const bf16x4s onesA = {oneb, oneb, oneb, oneb};
  const int swz = (lcol ^ lrow) * 8;

  auto stageKV = [&](int buf, int s0) {
#pragma unroll
    for (int i = 0; i < 2; i++) {
      const int r = wv * 16 + i * 8 + lrow;
      gld16(&kbh[(size_t)(s0 + r) * HD + swz],
            &Ks[buf][(wv * 16 + i * 8) * 64]);
      gld16(&vbh[(size_t)r * SS + s0 + swz],
            &Vs[buf][(wv * 16 + i * 8) * 64]);
    }
  };

  stageKV(0, kbase);

  for (int t = 0; t < 16; ++t) {
    __syncthreads();  // drains this tile's DMAs (issued one compute ago)
    if (t + 1 < 16) stageKV((t + 1) & 1, kbase + (t + 1) * 64);
    const bf16* Kc = Ks[t & 1];
    const bf16* Vc = Vs[t & 1];
    const unsigned long long sh0 = mrow[0][t] >> (quad * 4);
    const unsigned long long sh1 = mrow[1][t] >> (quad * 4);
    const unsigned lo0 = (unsigned)sh0, hi0 = (unsigned)(sh0 >> 32);
    const unsigned lo1 = (unsigned)sh1, hi1 = (unsigned)(sh1 >> 32);

#pragma unroll
    for (int ni = 0; ni < 4; ni++) {
      const int rr = ni * 16 + l15;
      const bf16x8 kf0 = *(const bf16x8*)&Kc[rr * 64 + (quad ^ (rr & 7)) * 8];
      const bf16x8 kf1 =
          *(const bf16x8*)&Kc[rr * 64 + ((4 + quad) ^ (rr & 7)) * 8];
      f32x4 a0 = {}, a1 = {};
      a0 = MFMA(kf0, aq[0][0], a0);
      a0 = MFMA(kf1, aq[0][1], a0);
      a1 = MFMA(kf0, aq[1][0], a1);
      a1 = MFMA(kf1, aq[1][1], a1);
      const unsigned nib0 = (ni == 0)   ? (lo0 & 0xF)
                            : (ni == 1) ? ((lo0 >> 16) & 0xF)
                            : (ni == 2) ? (hi0 & 0xF)
                                        : ((hi0 >> 16) & 0xF);
      const unsigned nib1 = (ni == 0)   ? (lo1 & 0xF)
                            : (ni == 1) ? ((lo1 >> 16) & 0xF)
                            : (ni == 2) ? (hi1 & 0xF)
                                        : ((hi1 >> 16) & 0xF);
      const uint2 mw0 = *(const uint2*)&lut[2 * nib0];
      const uint2 mw1 = *(const uint2*)&lut[2 * nib1];
      union {
        unsigned u[2];
        bf16x4s v;
      } p0, p1;
      p0.u[0] = pk2(__builtin_amdgcn_exp2f(a0[0]),
                    __builtin_amdgcn_exp2f(a0[1])) & mw0.x;
      p0.u[1] = pk2(__builtin_amdgcn_exp2f(a0[2]),
                    __builtin_amdgcn_exp2f(a0[3])) & mw0.y;
      p1.u[0] = pk2(__builtin_amdgcn_exp2f(a1[0]),
                    __builtin_amdgcn_exp2f(a1[1])) & mw1.x;
      p1.u[1] = pk2(__builtin_amdgcn_exp2f(a1[2]),
                    __builtin_amdgcn_exp2f(a1[3])) & mw1.y;
      lm[0] = MFMA16(onesA, p0.v, lm[0]);
      lm[1] = MFMA16(onesA, p1.v, lm[1]);
#pragma unroll
      for (int nd = 0; nd < 4; nd++) {
        const int row = nd * 16 + l15;
        const int pc = (ni * 2 + (quad >> 1)) ^ (row & 7);
        const bf16x4s vf =
            *(const bf16x4s*)&Vc[row * 64 + pc * 8 + (quad & 1) * 4];
        O[0][nd] = MFMA16(vf, p0.v, O[0][nd]);
        O[1][nd] = MFMA16(vf, p1.v, O[1][nd]);
      }
    }
  }

  // partial epilogue: un-normalized fp32 O + partial denominator
#pragma unroll
  for (int mi = 0; mi < 2; mi++) {
    const int sq = q0 + wv * 32 + mi * 16 + l15;
    float* od = Opart + ((size_t)ksl * BB * SS + (size_t)b * SS + sq) * DIM +
                h * HD + quad * 4;
#pragma unroll
    for (int nd = 0; nd < 4; nd++) {
      f32x4 o = O[mi][nd];
      *(f32x4*)&od[nd * 16] = o;
    }
    if (quad == 0)
      Lpart[(((size_t)ksl * BB + b) * NH + h) * SS + sq] = lm[mi][0];
  }
}

// ---------------- attention k-split reduce ---------------------------------
__global__ __launch_bounds__(256) void attn_reduce_kernel(
    const float* __restrict__ Op, const float* __restrict__ Lp,
    bf16* __restrict__ wa) {
  const int row = blockIdx.x;  // b*SS + s
  const int b = row >> 11, s = row & 2047;
  const int t = threadIdx.x;
#pragma unroll
  for (int j = 0; j < 3; j++) {
    const int d = t + j * 256;
    const int h = d >> 6;
    const float l = Lp[((size_t)b * NH + h) * SS + s] +
                    Lp[(((size_t)BB + b) * NH + h) * SS + s];
    const float o = Op[(size_t)row * DIM + d] +
                    Op[((size_t)BB * SS + row) * DIM + d];
    wa[(size_t)row * DIM + d] = (bf16)(o * __builtin_amdgcn_rcpf(l));
  }
}

// ---------------------------------------------------------------------------
extern "C" void kernel_launch(void* const* d_in, const int* in_sizes, int n_in,
                              void* d_out, int out_size, void* d_ws,
                              size_t ws_size, hipStream_t stream) {
  const float* x = (const float*)d_in[0];
  const int* mask = (const int*)d_in[1];
  const float* w_qkv = (const float*)d_in[2];
  const float* b_qkv = (const float*)d_in[3];
  const float* w_proj = (const float*)d_in[4];
  const float* b_proj = (const float*)d_in[5];
  const float* g1 = (const float*)d_in[6];
  const float* beta1 = (const float*)d_in[7];
  const float* g2 = (const float*)d_in[8];
  const float* beta2 = (const float*)d_in[9];
  const float* w1 = (const float*)d_in[10];
  const float* b1 = (const float*)d_in[11];
  const float* w2 = (const float*)d_in[12];
  const float* b2 = (const float*)d_in[13];
  float* out = (float*)d_out;

  char* p = (char*)d_ws;
  auto alloc = [&](size_t bytes) {
    char* r = p;
    p += (bytes + 1023) & ~(size_t)1023;
    return r;
  };
  bf16* wqkvT = (bf16*)alloc((size_t)2304 * 768 * 2);
  bf16* wprojT = (bf16*)alloc((size_t)768 * 768 * 2);
  bf16* w1T = (bf16*)alloc((size_t)3072 * 768 * 2);
  bf16* w2T = (bf16*)alloc((size_t)768 * 3072 * 2);
  unsigned* bits = (unsigned*)alloc((size_t)BB * SS * 64 * 4);
  bf16* h = (bf16*)alloc((size_t)8192 * 768 * 2);
  bf16* qb = (bf16*)alloc((size_t)8192 * 768 * 2);
  bf16* kb = (bf16*)alloc((size_t)8192 * 768 * 2);
  bf16* vtb = (bf16*)alloc((size_t)8192 * 768 * 2);
  bf16* wab = (bf16*)alloc((size_t)8192 * 768 * 2);
  float* x2 = (float*)alloc((size_t)8192 * 768 * 4);
  bf16* ffn1 = (bf16*)alloc((size_t)8192 * 3072 * 2);
  float* Opart = (float*)alloc((size_t)2 * 8192 * 768 * 4);
  float* Lpart = (float*)alloc((size_t)2 * BB * NH * SS * 4);

  // fused weight cast+transpose (one launch)
  castT_all_kernel<<<6912, 256, 0, stream>>>(w_qkv, wqkvT, w_proj, wprojT, w1,
                                             w1T, w2, w2T);
  // mask -> bits
  maskbits_kernel<<<(BB * SS * SS) / 256, 256, 0, stream>>>(mask, bits);
  // LN1
  ln_kernel<<<8192, 256, 0, stream>>>(x, g1, beta1, h);
  // QKV (V written pre-transposed, Q pre-scaled)
  gemm_kernel<EPI_QKV, 768>
      <<<dim3(2304 / 64, 8192 / 128), 256, 0, stream>>>(h, wqkvT, b_qkv,
                                                        nullptr, qb, kb, vtb);
  // attention (128 q-rows per block, 2 k-slices) + reduce
  attn_kernel<<<dim3((SS / 128) * 2, NH, BB), 256, 0, stream>>>(
      qb, kb, vtb, bits, Opart, Lpart);
  attn_reduce_kernel<<<BB * SS, 256, 0, stream>>>(Opart, Lpart, wab);
  // proj + residual
  gemm_kernel<EPI_PROJ, 768>
      <<<dim3(768 / 64, 8192 / 128), 256, 0, stream>>>(wab, wprojT, b_proj, x,
                                                       x2, nullptr, nullptr);
  // LN2
  ln_kernel<<<8192, 256, 0, stream>>>(x2, g2, beta2, h);
  // FFN1 + GELU
  gemm_kernel<EPI_FFN1, 768>
      <<<dim3(3072 / 64, 8192 / 128), 256, 0, stream>>>(h, w1T, b1, nullptr,
                                                        ffn1, nullptr,
                                                        nullptr);
  // FFN2 + residual -> out
  gemm_kernel<EPI_FFN2, 3072>
      <<<dim3(768 / 64, 8192 / 128), 256, 0, stream>>>(ffn1, w2T, b2, x2, out,
                                                       nullptr, nullptr);
}

// Round 11
// 514.472 us; speedup vs baseline: 1.0591x; 1.0591x over previous
//
#include <hip/hip_runtime.h>
#include <hip/hip_bf16.h>
#include <math.h>

typedef __bf16 bf16;
typedef __bf16 bf16x8 __attribute__((ext_vector_type(8)));
typedef short bf16x4s __attribute__((ext_vector_type(4)));
typedef float f32x4 __attribute__((ext_vector_type(4)));

#define DIM 768
#define NH 12
#define HD 64
#define HID 3072
#define BB 4
#define SS 2048
#define QPRESCALE 0.18033688011112042f /* (1/8) * log2(e) */

#define MFMA(a, b, c) __builtin_amdgcn_mfma_f32_16x16x32_bf16(a, b, c, 0, 0, 0)
#define MFMA16(a, b, c) \
  __builtin_amdgcn_mfma_f32_16x16x16bf16_1k(a, b, c, 0, 0, 0)

__device__ __forceinline__ void gld16(const void* g, void* l) {
  __builtin_amdgcn_global_load_lds(
      (const __attribute__((address_space(1))) void*)g,
      (__attribute__((address_space(3))) void*)l, 16, 0, 0);
}

__device__ __forceinline__ unsigned pk2(float a, float b) {
  union {
    bf16 h[2];
    unsigned u;
  } t;
  t.h[0] = (bf16)a;
  t.h[1] = (bf16)b;
  return t.u;
}

// ---------------- fused weight cast + transpose: fp32 [R][C] -> bf16 [C][R] -
__global__ __launch_bounds__(256) void castT_all_kernel(
    const float* __restrict__ s0, bf16* __restrict__ d0,
    const float* __restrict__ s1, bf16* __restrict__ d1,
    const float* __restrict__ s2, bf16* __restrict__ d2,
    const float* __restrict__ s3, bf16* __restrict__ d3) {
  __shared__ float tile[32][33];
  int id = blockIdx.x;
  const float* in;
  bf16* out;
  int R, C, loc;
  if (id < 1728) { in = s0; out = d0; R = 768; C = 2304; loc = id; }
  else if (id < 2304) { in = s1; out = d1; R = 768; C = 768; loc = id - 1728; }
  else if (id < 4608) { in = s2; out = d2; R = 768; C = 3072; loc = id - 2304; }
  else { in = s3; out = d3; R = 3072; C = 768; loc = id - 4608; }
  const int cb = C >> 5;
  const int c0 = (loc % cb) * 32, r0 = (loc / cb) * 32;
  const int tx = threadIdx.x & 31, ty = threadIdx.x >> 5;  // ty 0..7
#pragma unroll
  for (int i = 0; i < 32; i += 8)
    tile[ty + i][tx] = in[(size_t)(r0 + ty + i) * C + c0 + tx];
  __syncthreads();
#pragma unroll
  for (int i = 0; i < 32; i += 8)
    out[(size_t)(c0 + ty + i) * R + r0 + tx] = (bf16)tile[tx][ty + i];
}

// ---------------- mask int32 [B][1][S][S] -> bitmask [B][S][S/32] ----------
__global__ __launch_bounds__(256) void maskbits_kernel(
    const int* __restrict__ mask, unsigned* __restrict__ bits) {
  const int i = blockIdx.x * 256 + threadIdx.x;
  unsigned long long m = __ballot(mask[i] != 0);
  const int lane = threadIdx.x & 63;
  if (lane == 0) bits[i >> 5] = (unsigned)m;
  else if (lane == 32) bits[i >> 5] = (unsigned)(m >> 32);
}

// ---------------- LayerNorm fp32 row(768) -> bf16 --------------------------
__global__ __launch_bounds__(256) void ln_kernel(
    const float* __restrict__ x, const float* __restrict__ g,
    const float* __restrict__ beta, bf16* __restrict__ out) {
  const int row = blockIdx.x, t = threadIdx.x;
  const float* xr = x + (size_t)row * DIM;
  float v0 = xr[t], v1 = xr[t + 256], v2 = xr[t + 512];
  float s = v0 + v1 + v2;
  float s2 = v0 * v0 + v1 * v1 + v2 * v2;
#pragma unroll
  for (int d = 1; d < 64; d <<= 1) {
    s += __shfl_xor(s, d);
    s2 += __shfl_xor(s2, d);
  }
  __shared__ float red[8];
  const int wv = t >> 6, lane = t & 63;
  if (lane == 0) { red[wv] = s; red[wv + 4] = s2; }
  __syncthreads();
  s = red[0] + red[1] + red[2] + red[3];
  s2 = red[4] + red[5] + red[6] + red[7];
  const float mu = s * (1.0f / DIM);
  const float var = s2 * (1.0f / DIM) - mu * mu;
  const float r = rsqrtf(var + 1e-6f);
  bf16* o = out + (size_t)row * DIM;
  o[t] = (bf16)((v0 - mu) * r * g[t] + beta[t]);
  o[t + 256] = (bf16)((v1 - mu) * r * g[t + 256] + beta[t + 256]);
  o[t + 512] = (bf16)((v2 - mu) * r * g[t + 512] + beta[t + 512]);
}

// ---------------- GEMM: A[M][K] bf16 x Bt[N][K] bf16 -> epilogue -----------
// BK=64 (R10's BK=32 doubled barrier count per MFMA -> regressed).
// TN=64 fixed. TM=128: 4 waves x 32 rows (MI=2), dbuf LDS 48 KB, 3 blk/CU.
// TM=64: 4 waves x 16 rows (MI=1), dbuf LDS 32 KB, 5 blk/CU, grid x2 ->
// use for the block-starved proj/FFN2 (N=768 only).
// One barrier per iter; stage(next) issued right after the barrier into
// buf^1 (all waves' prior reads of buf^1 completed before that barrier).
enum { EPI_QKV = 0, EPI_PROJ = 1, EPI_FFN1 = 2, EPI_FFN2 = 3 };

template <int EPI, int K, int TM>
__global__ __launch_bounds__(256) void gemm_kernel(
    const bf16* __restrict__ A, const bf16* __restrict__ Bt,
    const float* __restrict__ bias, const float* __restrict__ res,
    void* __restrict__ o0, void* __restrict__ o1, void* __restrict__ o2) {
  constexpr int NIT = K / 64;
  constexpr int MI = TM / 64;              // 2 or 1
  constexpr int RPW = TM / 4;              // rows of A staged per wave
  __shared__ bf16 As[2][TM * 64];
  __shared__ bf16 Bs[2][64 * 64];
  const int tid = threadIdx.x;
  const int wv = tid >> 6, lane = tid & 63;
  const int quad = lane >> 4, l15 = lane & 15;
  const int lrow = lane >> 3, lcol = lane & 7;
  const int m0 = blockIdx.y * TM, n0 = blockIdx.x * 64;
  const int wm = wv * RPW;

  f32x4 acc[MI][4] = {};

  // staging: lane -> row lrow, slot lcol ; swizzled global chunk = lcol^lrow
  const int swz = (lcol ^ lrow) * 8;
  const bf16* Ag = A + (size_t)(m0 + wv * RPW + lrow) * K + swz;
  const bf16* Bg = Bt + (size_t)(n0 + wv * 16 + lrow) * K + swz;

  auto stage = [&](int buf, int k0) {
#pragma unroll
    for (int i = 0; i < RPW / 8; i++)
      gld16(Ag + (size_t)(i * 8) * K + k0, &As[buf][(wv * RPW + i * 8) * 64]);
#pragma unroll
    for (int i = 0; i < 2; i++)
      gld16(Bg + (size_t)(i * 8) * K + k0, &Bs[buf][(wv * 16 + i * 8) * 64]);
  };

  stage(0, 0);

  for (int it = 0; it < NIT; ++it) {
    __syncthreads();  // drains this iter's DMAs (issued one compute ago)
    if (it + 1 < NIT) stage((it + 1) & 1, (it + 1) * 64);
    const bf16* Ab = As[it & 1];
    const bf16* Bb = Bs[it & 1];
#pragma unroll
    for (int ks = 0; ks < 2; ks++) {
      bf16x8 af[MI], bfr[4];
#pragma unroll
      for (int i = 0; i < MI; i++) {
        const int ra = wm + i * 16 + l15;
        af[i] = *(const bf16x8*)&Ab[ra * 64 + ((ks * 4 + quad) ^ (ra & 7)) * 8];
      }
#pragma unroll
      for (int i = 0; i < 4; i++) {
        const int rb = i * 16 + l15;
        bfr[i] =
            *(const bf16x8*)&Bb[rb * 64 + ((ks * 4 + quad) ^ (rb & 7)) * 8];
      }
#pragma unroll
      for (int mi = 0; mi < MI; mi++)
#pragma unroll
        for (int ni = 0; ni < 4; ni++)
          acc[mi][ni] = MFMA(af[mi], bfr[ni], acc[mi][ni]);
    }
  }

  // epilogue: C layout col=lane&15, row=quad*4+reg
#pragma unroll
  for (int mi = 0; mi < MI; mi++) {
#pragma unroll
    for (int ni = 0; ni < 4; ni++) {
      const int n = n0 + ni * 16 + l15;
      const float bv = bias[n];
      const int mb = m0 + wm + mi * 16 + quad * 4;
      float val[4];
#pragma unroll
      for (int r = 0; r < 4; r++) val[r] = acc[mi][ni][r] + bv;
      if (EPI == EPI_QKV) {
        const int which = n / 768;
        const int nn = n - which * 768;
        const int hh = nn >> 6, d = nn & 63;
        const int bb = mb >> 11, s = mb & 2047;
        if (which == 0) {
#pragma unroll
          for (int r = 0; r < 4; r++)
            ((bf16*)o0)[((size_t)(bb * NH + hh) * SS + s + r) * HD + d] =
                (bf16)(val[r] * QPRESCALE);
        } else if (which == 1) {
#pragma unroll
          for (int r = 0; r < 4; r++)
            ((bf16*)o1)[((size_t)(bb * NH + hh) * SS + s + r) * HD + d] =
                (bf16)val[r];
        } else {
          // V transposed [bh][d][s]: 4 consecutive s -> packed 8B store
          uint2 pv;
          pv.x = pk2(val[0], val[1]);
          pv.y = pk2(val[2], val[3]);
          *(uint2*)&((bf16*)o2)[((size_t)(bb * NH + hh) * HD + d) * SS + s] = pv;
        }
      } else if (EPI == EPI_PROJ) {
#pragma unroll
        for (int r = 0; r < 4; r++)
          ((float*)o0)[(size_t)(mb + r) * DIM + n] =
              res[(size_t)(mb + r) * DIM + n] + val[r];
      } else if (EPI == EPI_FFN1) {
#pragma unroll
        for (int r = 0; r < 4; r++) {
          const float ge =
              0.5f * val[r] * (1.0f + erff(val[r] * 0.70710678118654752f));
          ((bf16*)o0)[(size_t)(mb + r) * HID + n] = (bf16)ge;
        }
      } else {  // EPI_FFN2
#pragma unroll
        for (int r = 0; r < 4; r++)
          ((float*)o0)[(size_t)(mb + r) * DIM + n] =
              res[(size_t)(mb + r) * DIM + n] + val[r];
      }
    }
  }
}

// ---------------- flash attention ------------------------------------------
// Sᵀ = MFMA(kfrag, qfrag) -> C layout (col=q, row=k) IS mfma16's B-frag
// layout, so PV needs no P movement. lsum via ones-A MFMA16 (row-sum of P).
// Mask via 16-entry LDS LUT on packed P. 128 q-rows/block (2 q-frags/wave)
// to amortize the per-wave K/V-tile LDS re-read. Double-buffered K/V with
// ONE barrier per tile (stage(next) after the barrier into buf^1).
__global__ __launch_bounds__(256) void attn_kernel(
    const bf16* __restrict__ q, const bf16* __restrict__ k,
    const bf16* __restrict__ vT, const unsigned* __restrict__ bits,
    bf16* __restrict__ wa) {
  const int b = blockIdx.z, h = blockIdx.y, q0 = blockIdx.x * 128;
  const int tid = threadIdx.x, wv = tid >> 6, lane = tid & 63;
  const int quad = lane >> 4, l15 = lane & 15;
  const int lrow = lane >> 3, lcol = lane & 7;

  __shared__ bf16 Ks[2][64 * 64];
  __shared__ bf16 Vs[2][64 * 64];
  __shared__ unsigned lut[32];

  if (tid < 16) {
    lut[2 * tid] =
        ((tid & 1) ? 0xFFFFu : 0u) | ((tid & 2) ? 0xFFFF0000u : 0u);
    lut[2 * tid + 1] =
        ((tid & 4) ? 0xFFFFu : 0u) | ((tid & 8) ? 0xFFFF0000u : 0u);
  }

  const bf16* qbh = q + (size_t)(b * NH + h) * SS * HD;
  const bf16* kbh = k + (size_t)(b * NH + h) * SS * HD;
  const bf16* vbh = vT + (size_t)(b * NH + h) * HD * SS;

  // Q fragments (B-operand for Sᵀ): q-row = q0 + wv*32 + mi*16 + l15
  bf16x8 aq[2][2];
#pragma unroll
  for (int mi = 0; mi < 2; mi++)
#pragma unroll
    for (int ks = 0; ks < 2; ks++) {
      const int s = q0 + wv * 32 + mi * 16 + l15;
      aq[mi][ks] = *(const bf16x8*)&qbh[(size_t)s * HD + ks * 32 + quad * 8];
    }

  const unsigned long long* mrow[2];
#pragma unroll
  for (int mi = 0; mi < 2; mi++)
    mrow[mi] = (const unsigned long long*)bits +
               (size_t)(b * SS + q0 + wv * 32 + mi * 16 + l15) * 32;

  f32x4 O[2][4] = {};
  f32x4 lm[2] = {};
  const short oneb = 0x3F80;
  const bf16x4s onesA = {oneb, oneb, oneb, oneb};
  const int swz = (lcol ^ lrow) * 8;

  auto stageKV = [&](int buf, int s0) {
#pragma unroll
    for (int i = 0; i < 2; i++) {
      const int r = wv * 16 + i * 8 + lrow;
      gld16(&kbh[(size_t)(s0 + r) * HD + swz],
            &Ks[buf][(wv * 16 + i * 8) * 64]);
      gld16(&vbh[(size_t)r * SS + s0 + swz],
            &Vs[buf][(wv * 16 + i * 8) * 64]);
    }
  };

  stageKV(0, 0);

  for (int t = 0; t < SS / 64; ++t) {
    __syncthreads();  // drains this tile's DMAs (issued one compute ago)
    if (t + 1 < SS / 64) stageKV((t + 1) & 1, (t + 1) * 64);
    const bf16* Kc = Ks[t & 1];
    const bf16* Vc = Vs[t & 1];
    const unsigned long long sh0 = mrow[0][t] >> (quad * 4);
    const unsigned long long sh1 = mrow[1][t] >> (quad * 4);
    const unsigned lo0 = (unsigned)sh0, hi0 = (unsigned)(sh0 >> 32);
    const unsigned lo1 = (unsigned)sh1, hi1 = (unsigned)(sh1 >> 32);

#pragma unroll
    for (int ni = 0; ni < 4; ni++) {
      const int rr = ni * 16 + l15;
      const bf16x8 kf0 = *(const bf16x8*)&Kc[rr * 64 + (quad ^ (rr & 7)) * 8];
      const bf16x8 kf1 =
          *(const bf16x8*)&Kc[rr * 64 + ((4 + quad) ^ (rr & 7)) * 8];
      f32x4 a0 = {}, a1 = {};
      a0 = MFMA(kf0, aq[0][0], a0);
      a0 = MFMA(kf1, aq[0][1], a0);
      a1 = MFMA(kf0, aq[1][0], a1);
      a1 = MFMA(kf1, aq[1][1], a1);
      const unsigned nib0 = (ni == 0)   ? (lo0 & 0xF)
                            : (ni == 1) ? ((lo0 >> 16) & 0xF)
                            : (ni == 2) ? (hi0 & 0xF)
                                        : ((hi0 >> 16) & 0xF);
      const unsigned nib1 = (ni == 0)   ? (lo1 & 0xF)
                            : (ni == 1) ? ((lo1 >> 16) & 0xF)
                            : (ni == 2) ? (hi1 & 0xF)
                                        : ((hi1 >> 16) & 0xF);
      const uint2 mw0 = *(const uint2*)&lut[2 * nib0];
      const uint2 mw1 = *(const uint2*)&lut[2 * nib1];
      union {
        unsigned u[2];
        bf16x4s v;
      } p0, p1;
      p0.u[0] = pk2(__builtin_amdgcn_exp2f(a0[0]),
                    __builtin_amdgcn_exp2f(a0[1])) & mw0.x;
      p0.u[1] = pk2(__builtin_amdgcn_exp2f(a0[2]),
                    __builtin_amdgcn_exp2f(a0[3])) & mw0.y;
      p1.u[0] = pk2(__builtin_amdgcn_exp2f(a1[0]),
                    __builtin_amdgcn_exp2f(a1[1])) & mw1.x;
      p1.u[1] = pk2(__builtin_amdgcn_exp2f(a1[2]),
                    __builtin_amdgcn_exp2f(a1[3])) & mw1.y;
      lm[0] = MFMA16(onesA, p0.v, lm[0]);
      lm[1] = MFMA16(onesA, p1.v, lm[1]);
#pragma unroll
      for (int nd = 0; nd < 4; nd++) {
        const int row = nd * 16 + l15;
        const int pc = (ni * 2 + (quad >> 1)) ^ (row & 7);
        const bf16x4s vf =
            *(const bf16x4s*)&Vc[row * 64 + pc * 8 + (quad & 1) * 4];
        O[0][nd] = MFMA16(vf, p0.v, O[0][nd]);
        O[1][nd] = MFMA16(vf, p1.v, O[1][nd]);
      }
    }
  }

  // lm[mi][r] (any r) = full softmax denominator for this lane's q-row
#pragma unroll
  for (int mi = 0; mi < 2; mi++) {
    const float rln = __builtin_amdgcn_rcpf(lm[mi][0]);
    const int sq = q0 + wv * 32 + mi * 16 + l15;
    bf16* dst = wa + (size_t)(b * SS + sq) * DIM + h * HD + quad * 4;
#pragma unroll
    for (int nd = 0; nd < 4; nd++) {
      uint2 pv;
      pv.x = pk2(O[mi][nd][0] * rln, O[mi][nd][1] * rln);
      pv.y = pk2(O[mi][nd][2] * rln, O[mi][nd][3] * rln);
      *(uint2*)&dst[nd * 16] = pv;
    }
  }
}

// ---------------------------------------------------------------------------
extern "C" void kernel_launch(void* const* d_in, const int* in_sizes, int n_in,
                              void* d_out, int out_size, void* d_ws,
                              size_t ws_size, hipStream_t stream) {
  const float* x = (const float*)d_in[0];
  const int* mask = (const int*)d_in[1];
  const float* w_qkv = (const float*)d_in[2];
  const float* b_qkv = (const float*)d_in[3];
  const float* w_proj = (const float*)d_in[4];
  const float* b_proj = (const float*)d_in[5];
  const float* g1 = (const float*)d_in[6];
  const float* beta1 = (const float*)d_in[7];
  const float* g2 = (const float*)d_in[8];
  const float* beta2 = (const float*)d_in[9];
  const float* w1 = (const float*)d_in[10];
  const float* b1 = (const float*)d_in[11];
  const float* w2 = (const float*)d_in[12];
  const float* b2 = (const float*)d_in[13];
  float* out = (float*)d_out;

  char* p = (char*)d_ws;
  auto alloc = [&](size_t bytes) {
    char* r = p;
    p += (bytes + 1023) & ~(size_t)1023;
    return r;
  };
  bf16* wqkvT = (bf16*)alloc((size_t)2304 * 768 * 2);
  bf16* wprojT = (bf16*)alloc((size_t)768 * 768 * 2);
  bf16* w1T = (bf16*)alloc((size_t)3072 * 768 * 2);
  bf16* w2T = (bf16*)alloc((size_t)768 * 3072 * 2);
  unsigned* bits = (unsigned*)alloc((size_t)BB * SS * 64 * 4);
  bf16* h = (bf16*)alloc((size_t)8192 * 768 * 2);
  bf16* qb = (bf16*)alloc((size_t)8192 * 768 * 2);
  bf16* kb = (bf16*)alloc((size_t)8192 * 768 * 2);
  bf16* vtb = (bf16*)alloc((size_t)8192 * 768 * 2);
  bf16* wab = (bf16*)alloc((size_t)8192 * 768 * 2);
  float* x2 = (float*)alloc((size_t)8192 * 768 * 4);
  bf16* ffn1 = (bf16*)alloc((size_t)8192 * 3072 * 2);

  // fused weight cast+transpose (one launch)
  castT_all_kernel<<<6912, 256, 0, stream>>>(w_qkv, wqkvT, w_proj, wprojT, w1,
                                             w1T, w2, w2T);
  // mask -> bits
  maskbits_kernel<<<(BB * SS * SS) / 256, 256, 0, stream>>>(mask, bits);
  // LN1
  ln_kernel<<<8192, 256, 0, stream>>>(x, g1, beta1, h);
  // QKV (V written pre-transposed, Q pre-scaled), TM=128
  gemm_kernel<EPI_QKV, 768, 128>
      <<<dim3(2304 / 64, 8192 / 128), 256, 0, stream>>>(h, wqkvT, b_qkv,
                                                        nullptr, qb, kb, vtb);
  // attention (128 q-rows per block, dbuf K/V)
  attn_kernel<<<dim3(SS / 128, NH, BB), 256, 0, stream>>>(qb, kb, vtb, bits,
                                                          wab);
  // proj + residual, TM=64 (block-starved N=768 -> grid 1536)
  gemm_kernel<EPI_PROJ, 768, 64>
      <<<dim3(768 / 64, 8192 / 64), 256, 0, stream>>>(wab, wprojT, b_proj, x,
                                                      x2, nullptr, nullptr);
  // LN2
  ln_kernel<<<8192, 256, 0, stream>>>(x2, g2, beta2, h);
  // FFN1 + GELU, TM=128
  gemm_kernel<EPI_FFN1, 768, 128>
      <<<dim3(3072 / 64, 8192 / 128), 256, 0, stream>>>(h, w1T, b1, nullptr,
                                                        ffn1, nullptr,
                                                        nullptr);
  // FFN2 + residual -> out, TM=64 (grid 1536, K=3072 deep pipe)
  gemm_kernel<EPI_FFN2, 3072, 64>
      <<<dim3(768 / 64, 8192 / 64), 256, 0, stream>>>(ffn1, w2T, b2, x2, out,
                                                      nullptr, nullptr);
}

// Round 12
// 464.791 us; speedup vs baseline: 1.1723x; 1.1069x over previous
//
#include <hip/hip_runtime.h>
#include <hip/hip_bf16.h>
#include <math.h>

typedef __bf16 bf16;
typedef __bf16 bf16x8 __attribute__((ext_vector_type(8)));
typedef short bf16x4s __attribute__((ext_vector_type(4)));
typedef float f32x4 __attribute__((ext_vector_type(4)));

#define DIM 768
#define NH 12
#define HD 64
#define HID 3072
#define BB 4
#define SS 2048
#define QPRESCALE 0.18033688011112042f /* (1/8) * log2(e) */

#define MFMA(a, b, c) __builtin_amdgcn_mfma_f32_16x16x32_bf16(a, b, c, 0, 0, 0)
#define MFMA16(a, b, c) \
  __builtin_amdgcn_mfma_f32_16x16x16bf16_1k(a, b, c, 0, 0, 0)

__device__ __forceinline__ void gld16(const void* g, void* l) {
  __builtin_amdgcn_global_load_lds(
      (const __attribute__((address_space(1))) void*)g,
      (__attribute__((address_space(3))) void*)l, 16, 0, 0);
}

__device__ __forceinline__ unsigned pk2(float a, float b) {
  union {
    bf16 h[2];
    unsigned u;
  } t;
  t.h[0] = (bf16)a;
  t.h[1] = (bf16)b;
  return t.u;
}

// ---------------- fused prologue: castT x4 + maskbits + LN1 -----------------
// Independent preprocessing fused into ONE launch (removes serialized launch
// gaps; the three phases were ~35us as separate kernels).
// id < 6912            : weight cast+transpose fp32 [R][C] -> bf16 [C][R]
// id < 6912+65536      : mask int32 -> bitmask
// else (8192 blocks)   : LayerNorm1 row -> bf16
__global__ __launch_bounds__(256) void prologue_kernel(
    const float* __restrict__ s0, bf16* __restrict__ d0,
    const float* __restrict__ s1, bf16* __restrict__ d1,
    const float* __restrict__ s2, bf16* __restrict__ d2,
    const float* __restrict__ s3, bf16* __restrict__ d3,
    const int* __restrict__ mask, unsigned* __restrict__ bits,
    const float* __restrict__ x, const float* __restrict__ g,
    const float* __restrict__ beta, bf16* __restrict__ out) {
  const int bid = blockIdx.x;
  if (bid < 6912) {
    __shared__ float tile[32][33];
    int id = bid;
    const float* in;
    bf16* o;
    int R, C, loc;
    if (id < 1728) { in = s0; o = d0; R = 768; C = 2304; loc = id; }
    else if (id < 2304) { in = s1; o = d1; R = 768; C = 768; loc = id - 1728; }
    else if (id < 4608) { in = s2; o = d2; R = 768; C = 3072; loc = id - 2304; }
    else { in = s3; o = d3; R = 3072; C = 768; loc = id - 4608; }
    const int cb = C >> 5;
    const int c0 = (loc % cb) * 32, r0 = (loc / cb) * 32;
    const int tx = threadIdx.x & 31, ty = threadIdx.x >> 5;
#pragma unroll
    for (int i = 0; i < 32; i += 8)
      tile[ty + i][tx] = in[(size_t)(r0 + ty + i) * C + c0 + tx];
    __syncthreads();
#pragma unroll
    for (int i = 0; i < 32; i += 8)
      o[(size_t)(c0 + ty + i) * R + r0 + tx] = (bf16)tile[tx][ty + i];
  } else if (bid < 6912 + 65536) {
    const int i = (bid - 6912) * 256 + threadIdx.x;
    unsigned long long m = __ballot(mask[i] != 0);
    const int lane = threadIdx.x & 63;
    if (lane == 0) bits[i >> 5] = (unsigned)m;
    else if (lane == 32) bits[i >> 5] = (unsigned)(m >> 32);
  } else {
    const int row = bid - (6912 + 65536), t = threadIdx.x;
    const float* xr = x + (size_t)row * DIM;
    float v0 = xr[t], v1 = xr[t + 256], v2 = xr[t + 512];
    float s = v0 + v1 + v2;
    float s2 = v0 * v0 + v1 * v1 + v2 * v2;
#pragma unroll
    for (int d = 1; d < 64; d <<= 1) {
      s += __shfl_xor(s, d);
      s2 += __shfl_xor(s2, d);
    }
    __shared__ float red[8];
    const int wv = t >> 6, lane = t & 63;
    if (lane == 0) { red[wv] = s; red[wv + 4] = s2; }
    __syncthreads();
    s = red[0] + red[1] + red[2] + red[3];
    s2 = red[4] + red[5] + red[6] + red[7];
    const float mu = s * (1.0f / DIM);
    const float var = s2 * (1.0f / DIM) - mu * mu;
    const float r = rsqrtf(var + 1e-6f);
    bf16* o = out + (size_t)row * DIM;
    o[t] = (bf16)((v0 - mu) * r * g[t] + beta[t]);
    o[t + 256] = (bf16)((v1 - mu) * r * g[t + 256] + beta[t + 256]);
    o[t + 512] = (bf16)((v2 - mu) * r * g[t + 512] + beta[t + 512]);
  }
}

// ---------------- LayerNorm fp32 row(768) -> bf16 (LN2) ---------------------
__global__ __launch_bounds__(256) void ln_kernel(
    const float* __restrict__ x, const float* __restrict__ g,
    const float* __restrict__ beta, bf16* __restrict__ out) {
  const int row = blockIdx.x, t = threadIdx.x;
  const float* xr = x + (size_t)row * DIM;
  float v0 = xr[t], v1 = xr[t + 256], v2 = xr[t + 512];
  float s = v0 + v1 + v2;
  float s2 = v0 * v0 + v1 * v1 + v2 * v2;
#pragma unroll
  for (int d = 1; d < 64; d <<= 1) {
    s += __shfl_xor(s, d);
    s2 += __shfl_xor(s2, d);
  }
  __shared__ float red[8];
  const int wv = t >> 6, lane = t & 63;
  if (lane == 0) { red[wv] = s; red[wv + 4] = s2; }
  __syncthreads();
  s = red[0] + red[1] + red[2] + red[3];
  s2 = red[4] + red[5] + red[6] + red[7];
  const float mu = s * (1.0f / DIM);
  const float var = s2 * (1.0f / DIM) - mu * mu;
  const float r = rsqrtf(var + 1e-6f);
  bf16* o = out + (size_t)row * DIM;
  o[t] = (bf16)((v0 - mu) * r * g[t] + beta[t]);
  o[t + 256] = (bf16)((v1 - mu) * r * g[t + 256] + beta[t + 256]);
  o[t + 512] = (bf16)((v2 - mu) * r * g[t + 512] + beta[t + 512]);
}

// ---------------- GEMM: A[M][K] bf16 x Bt[N][K] bf16 -> epilogue -----------
// R9 structure (best: 494us): TM=128, TN=64, BK=64, 4 waves of 32x64,
// dbuf LDS 48 KB, ONE barrier/iter (stage(next) after barrier into buf^1).
// NEW: 1-D grid, XCD-aware remap: by = id % 64, bx = id / 64. Since
// 64 % 8 XCDs == 0, all blocks sharing an A-tile (same by) land on the SAME
// XCD -> A fetched from HBM ~once per XCD instead of ~8x, A-reads hit local
// L2 (200cyc vs 900) which is what this latency-bound pipeline needs.
enum { EPI_QKV = 0, EPI_PROJ = 1, EPI_FFN1 = 2, EPI_FFN2 = 3 };

template <int EPI, int K>
__global__ __launch_bounds__(256) void gemm_kernel(
    const bf16* __restrict__ A, const bf16* __restrict__ Bt,
    const float* __restrict__ bias, const float* __restrict__ res,
    void* __restrict__ o0, void* __restrict__ o1, void* __restrict__ o2) {
  constexpr int NIT = K / 64;
  __shared__ bf16 As[2][128 * 64];
  __shared__ bf16 Bs[2][64 * 64];
  const int tid = threadIdx.x;
  const int wv = tid >> 6, lane = tid & 63;
  const int quad = lane >> 4, l15 = lane & 15;
  const int lrow = lane >> 3, lcol = lane & 7;
  const int id = blockIdx.x;
  const int m0 = (id & 63) * 128, n0 = (id >> 6) * 64;  // XCD-friendly remap
  const int wm = wv * 32;

  f32x4 acc[2][4] = {};

  // staging: lane -> row lrow, slot lcol ; swizzled global chunk = lcol^lrow
  const int swz = (lcol ^ lrow) * 8;
  const bf16* Ag = A + (size_t)(m0 + wv * 32 + lrow) * K + swz;
  const bf16* Bg = Bt + (size_t)(n0 + wv * 16 + lrow) * K + swz;

  auto stage = [&](int buf, int k0) {
#pragma unroll
    for (int i = 0; i < 4; i++)
      gld16(Ag + (size_t)(i * 8) * K + k0, &As[buf][(wv * 32 + i * 8) * 64]);
#pragma unroll
    for (int i = 0; i < 2; i++)
      gld16(Bg + (size_t)(i * 8) * K + k0, &Bs[buf][(wv * 16 + i * 8) * 64]);
  };

  stage(0, 0);

  for (int it = 0; it < NIT; ++it) {
    __syncthreads();  // drains this iter's DMAs (issued one compute ago)
    if (it + 1 < NIT) stage((it + 1) & 1, (it + 1) * 64);
    const bf16* Ab = As[it & 1];
    const bf16* Bb = Bs[it & 1];
#pragma unroll
    for (int ks = 0; ks < 2; ks++) {
      bf16x8 af[2], bfr[4];
#pragma unroll
      for (int i = 0; i < 2; i++) {
        const int ra = wm + i * 16 + l15;
        af[i] = *(const bf16x8*)&Ab[ra * 64 + ((ks * 4 + quad) ^ (ra & 7)) * 8];
      }
#pragma unroll
      for (int i = 0; i < 4; i++) {
        const int rb = i * 16 + l15;
        bfr[i] =
            *(const bf16x8*)&Bb[rb * 64 + ((ks * 4 + quad) ^ (rb & 7)) * 8];
      }
#pragma unroll
      for (int mi = 0; mi < 2; mi++)
#pragma unroll
        for (int ni = 0; ni < 4; ni++)
          acc[mi][ni] = MFMA(af[mi], bfr[ni], acc[mi][ni]);
    }
  }

  // epilogue: C layout col=lane&15, row=quad*4+reg
#pragma unroll
  for (int mi = 0; mi < 2; mi++) {
#pragma unroll
    for (int ni = 0; ni < 4; ni++) {
      const int n = n0 + ni * 16 + l15;
      const float bv = bias[n];
      const int mb = m0 + wm + mi * 16 + quad * 4;
      float val[4];
#pragma unroll
      for (int r = 0; r < 4; r++) val[r] = acc[mi][ni][r] + bv;
      if (EPI == EPI_QKV) {
        const int which = n / 768;
        const int nn = n - which * 768;
        const int hh = nn >> 6, d = nn & 63;
        const int bb = mb >> 11, s = mb & 2047;
        if (which == 0) {
#pragma unroll
          for (int r = 0; r < 4; r++)
            ((bf16*)o0)[((size_t)(bb * NH + hh) * SS + s + r) * HD + d] =
                (bf16)(val[r] * QPRESCALE);
        } else if (which == 1) {
#pragma unroll
          for (int r = 0; r < 4; r++)
            ((bf16*)o1)[((size_t)(bb * NH + hh) * SS + s + r) * HD + d] =
                (bf16)val[r];
        } else {
          // V transposed [bh][d][s]: 4 consecutive s -> packed 8B store
          uint2 pv;
          pv.x = pk2(val[0], val[1]);
          pv.y = pk2(val[2], val[3]);
          *(uint2*)&((bf16*)o2)[((size_t)(bb * NH + hh) * HD + d) * SS + s] = pv;
        }
      } else if (EPI == EPI_PROJ) {
#pragma unroll
        for (int r = 0; r < 4; r++)
          ((float*)o0)[(size_t)(mb + r) * DIM + n] =
              res[(size_t)(mb + r) * DIM + n] + val[r];
      } else if (EPI == EPI_FFN1) {
#pragma unroll
        for (int r = 0; r < 4; r++) {
          const float ge =
              0.5f * val[r] * (1.0f + erff(val[r] * 0.70710678118654752f));
          ((bf16*)o0)[(size_t)(mb + r) * HID + n] = (bf16)ge;
        }
      } else {  // EPI_FFN2
#pragma unroll
        for (int r = 0; r < 4; r++)
          ((float*)o0)[(size_t)(mb + r) * DIM + n] =
              res[(size_t)(mb + r) * DIM + n] + val[r];
      }
    }
  }
}

// ---------------- flash attention (R9 structure, best: 102us) ---------------
// Sᵀ = MFMA(kfrag, qfrag) -> C layout (col=q, row=k) IS mfma16's B-frag
// layout, so PV needs no P movement. lsum via ones-A MFMA16 (row-sum of P).
// Mask via 16-entry LDS LUT on packed P. 128 q-rows/block (2 q-frags/wave).
// Single-buffered K/V: explicit dbuf measured +6us here (R11) — the implicit
// wave-level overlap at 3 blk/CU already covers the staging latency.
__global__ __launch_bounds__(256) void attn_kernel(
    const bf16* __restrict__ q, const bf16* __restrict__ k,
    const bf16* __restrict__ vT, const unsigned* __restrict__ bits,
    bf16* __restrict__ wa) {
  const int b = blockIdx.z, h = blockIdx.y, q0 = blockIdx.x * 128;
  const int tid = threadIdx.x, wv = tid >> 6, lane = tid & 63;
  const int quad = lane >> 4, l15 = lane & 15;
  const int lrow = lane >> 3, lcol = lane & 7;

  __shared__ bf16 Ks[64 * 64];
  __shared__ bf16 Vs[64 * 64];
  __shared__ unsigned lut[32];

  if (tid < 16) {
    lut[2 * tid] =
        ((tid & 1) ? 0xFFFFu : 0u) | ((tid & 2) ? 0xFFFF0000u : 0u);
    lut[2 * tid + 1] =
        ((tid & 4) ? 0xFFFFu : 0u) | ((tid & 8) ? 0xFFFF0000u : 0u);
  }

  const bf16* qbh = q + (size_t)(b * NH + h) * SS * HD;
  const bf16* kbh = k + (size_t)(b * NH + h) * SS * HD;
  const bf16* vbh = vT + (size_t)(b * NH + h) * HD * SS;

  // Q fragments (B-operand for Sᵀ): q-row = q0 + wv*32 + mi*16 + l15
  bf16x8 aq[2][2];
#pragma unroll
  for (int mi = 0; mi < 2; mi++)
#pragma unroll
    for (int ks = 0; ks < 2; ks++) {
      const int s = q0 + wv * 32 + mi * 16 + l15;
      aq[mi][ks] = *(const bf16x8*)&qbh[(size_t)s * HD + ks * 32 + quad * 8];
    }

  const unsigned long long* mrow[2];
#pragma unroll
  for (int mi = 0; mi < 2; mi++)
    mrow[mi] = (const unsigned long long*)bits +
               (size_t)(b * SS + q0 + wv * 32 + mi * 16 + l15) * 32;

  f32x4 O[2][4] = {};
  f32x4 lm[2] = {};
  const short oneb = 0x3F80;
  const bf16x4s onesA = {oneb, oneb, oneb, oneb};
  const int swz = (lcol ^ lrow) * 8;

  for (int t = 0; t < SS / 64; ++t) {
    const int s0 = t * 64;
    // stage K[s0..+64][0..64] and Vᵀ[0..64][s0..+64] (XOR-chunk swizzle)
#pragma unroll
    for (int i = 0; i < 2; i++) {
      const int r = wv * 16 + i * 8 + lrow;
      gld16(&kbh[(size_t)(s0 + r) * HD + swz], &Ks[(wv * 16 + i * 8) * 64]);
      gld16(&vbh[(size_t)r * SS + s0 + swz], &Vs[(wv * 16 + i * 8) * 64]);
    }
    const unsigned long long sh0 = mrow[0][t] >> (quad * 4);
    const unsigned long long sh1 = mrow[1][t] >> (quad * 4);
    const unsigned lo0 = (unsigned)sh0, hi0 = (unsigned)(sh0 >> 32);
    const unsigned lo1 = (unsigned)sh1, hi1 = (unsigned)(sh1 >> 32);
    __syncthreads();

#pragma unroll
    for (int ni = 0; ni < 4; ni++) {
      const int rr = ni * 16 + l15;
      const bf16x8 kf0 = *(const bf16x8*)&Ks[rr * 64 + (quad ^ (rr & 7)) * 8];
      const bf16x8 kf1 =
          *(const bf16x8*)&Ks[rr * 64 + ((4 + quad) ^ (rr & 7)) * 8];
      f32x4 a0 = {}, a1 = {};
      a0 = MFMA(kf0, aq[0][0], a0);
      a0 = MFMA(kf1, aq[0][1], a0);
      a1 = MFMA(kf0, aq[1][0], a1);
      a1 = MFMA(kf1, aq[1][1], a1);
      const unsigned nib0 = (ni == 0)   ? (lo0 & 0xF)
                            : (ni == 1) ? ((lo0 >> 16) & 0xF)
                            : (ni == 2) ? (hi0 & 0xF)
                                        : ((hi0 >> 16) & 0xF);
      const unsigned nib1 = (ni == 0)   ? (lo1 & 0xF)
                            : (ni == 1) ? ((lo1 >> 16) & 0xF)
                            : (ni == 2) ? (hi1 & 0xF)
                                        : ((hi1 >> 16) & 0xF);
      const uint2 mw0 = *(const uint2*)&lut[2 * nib0];
      const uint2 mw1 = *(const uint2*)&lut[2 * nib1];
      union {
        unsigned u[2];
        bf16x4s v;
      } p0, p1;
      p0.u[0] = pk2(__builtin_amdgcn_exp2f(a0[0]),
                    __builtin_amdgcn_exp2f(a0[1])) & mw0.x;
      p0.u[1] = pk2(__builtin_amdgcn_exp2f(a0[2]),
                    __builtin_amdgcn_exp2f(a0[3])) & mw0.y;
      p1.u[0] = pk2(__builtin_amdgcn_exp2f(a1[0]),
                    __builtin_amdgcn_exp2f(a1[1])) & mw1.x;
      p1.u[1] = pk2(__builtin_amdgcn_exp2f(a1[2]),
                    __builtin_amdgcn_exp2f(a1[3])) & mw1.y;
      lm[0] = MFMA16(onesA, p0.v, lm[0]);
      lm[1] = MFMA16(onesA, p1.v, lm[1]);
#pragma unroll
      for (int nd = 0; nd < 4; nd++) {
        const int row = nd * 16 + l15;
        const int pc = (ni * 2 + (quad >> 1)) ^ (row & 7);
        const bf16x4s vf =
            *(const bf16x4s*)&Vs[row * 64 + pc * 8 + (quad & 1) * 4];
        O[0][nd] = MFMA16(vf, p0.v, O[0][nd]);
        O[1][nd] = MFMA16(vf, p1.v, O[1][nd]);
      }
    }
    __syncthreads();
  }

  // lm[mi][r] (any r) = full softmax denominator for this lane's q-row
#pragma unroll
  for (int mi = 0; mi < 2; mi++) {
    const float rln = __builtin_amdgcn_rcpf(lm[mi][0]);
    const int sq = q0 + wv * 32 + mi * 16 + l15;
    bf16* dst = wa + (size_t)(b * SS + sq) * DIM + h * HD + quad * 4;
#pragma unroll
    for (int nd = 0; nd < 4; nd++) {
      uint2 pv;
      pv.x = pk2(O[mi][nd][0] * rln, O[mi][nd][1] * rln);
      pv.y = pk2(O[mi][nd][2] * rln, O[mi][nd][3] * rln);
      *(uint2*)&dst[nd * 16] = pv;
    }
  }
}

// ---------------------------------------------------------------------------
extern "C" void kernel_launch(void* const* d_in, const int* in_sizes, int n_in,
                              void* d_out, int out_size, void* d_ws,
                              size_t ws_size, hipStream_t stream) {
  const float* x = (const float*)d_in[0];
  const int* mask = (const int*)d_in[1];
  const float* w_qkv = (const float*)d_in[2];
  const float* b_qkv = (const float*)d_in[3];
  const float* w_proj = (const float*)d_in[4];
  const float* b_proj = (const float*)d_in[5];
  const float* g1 = (const float*)d_in[6];
  const float* beta1 = (const float*)d_in[7];
  const float* g2 = (const float*)d_in[8];
  const float* beta2 = (const float*)d_in[9];
  const float* w1 = (const float*)d_in[10];
  const float* b1 = (const float*)d_in[11];
  const float* w2 = (const float*)d_in[12];
  const float* b2 = (const float*)d_in[13];
  float* out = (float*)d_out;

  char* p = (char*)d_ws;
  auto alloc = [&](size_t bytes) {
    char* r = p;
    p += (bytes + 1023) & ~(size_t)1023;
    return r;
  };
  bf16* wqkvT = (bf16*)alloc((size_t)2304 * 768 * 2);
  bf16* wprojT = (bf16*)alloc((size_t)768 * 768 * 2);
  bf16* w1T = (bf16*)alloc((size_t)3072 * 768 * 2);
  bf16* w2T = (bf16*)alloc((size_t)768 * 3072 * 2);
  unsigned* bits = (unsigned*)alloc((size_t)BB * SS * 64 * 4);
  bf16* h = (bf16*)alloc((size_t)8192 * 768 * 2);
  bf16* qb = (bf16*)alloc((size_t)8192 * 768 * 2);
  bf16* kb = (bf16*)alloc((size_t)8192 * 768 * 2);
  bf16* vtb = (bf16*)alloc((size_t)8192 * 768 * 2);
  bf16* wab = (bf16*)alloc((size_t)8192 * 768 * 2);
  float* x2 = (float*)alloc((size_t)8192 * 768 * 4);
  bf16* ffn1 = (bf16*)alloc((size_t)8192 * 3072 * 2);

  // fused prologue: weight castT x4 + mask->bits + LN1 (one launch)
  prologue_kernel<<<6912 + 65536 + 8192, 256, 0, stream>>>(
      w_qkv, wqkvT, w_proj, wprojT, w1, w1T, w2, w2T, mask, bits, x, g1,
      beta1, h);
  // QKV (V written pre-transposed, Q pre-scaled); grid = 64 m-blocks x 36 n
  gemm_kernel<EPI_QKV, 768><<<64 * 36, 256, 0, stream>>>(h, wqkvT, b_qkv,
                                                         nullptr, qb, kb, vtb);
  // attention (128 q-rows per block)
  attn_kernel<<<dim3(SS / 128, NH, BB), 256, 0, stream>>>(qb, kb, vtb, bits,
                                                          wab);
  // proj + residual; 64 x 12
  gemm_kernel<EPI_PROJ, 768><<<64 * 12, 256, 0, stream>>>(wab, wprojT, b_proj,
                                                          x, x2, nullptr,
                                                          nullptr);
  // LN2
  ln_kernel<<<8192, 256, 0, stream>>>(x2, g2, beta2, h);
  // FFN1 + GELU; 64 x 48
  gemm_kernel<EPI_FFN1, 768><<<64 * 48, 256, 0, stream>>>(h, w1T, b1, nullptr,
                                                          ffn1, nullptr,
                                                          nullptr);
  // FFN2 + residual -> out; 64 x 12
  gemm_kernel<EPI_FFN2, 3072><<<64 * 12, 256, 0, stream>>>(ffn1, w2T, b2, x2,
                                                           out, nullptr,
                                                           nullptr);
}